// Round 1
// baseline (159.463 us; speedup 1.0000x reference)
//
#include <hip/hip_runtime.h>

typedef unsigned long long u64;

#define FILE0 0x0101010101010101ULL  // col j=0
#define NF0   0xFEFEFEFEFEFEFEFEULL  // ~FILE0
#define NF7   0x7F7F7F7F7F7F7F7FULL  // ~FILE7

// Directions: 0=(0,1) rows, 1=(1,0) cols, 2=(1,1) diag, 3=(1,-1) anti-diag
// SH<D>(x): position p reads p-d (backward shift). FW<D>(x): p reads p+d.
template<int D> __device__ __forceinline__ u64 SH(u64 x) {
  if (D == 0) return (x << 1) & NF0;
  if (D == 1) return x << 8;
  if (D == 2) return (x << 9) & NF0;
  return (x << 7) & NF7;            // (1,-1): m[i-1][j+1]
}
template<int D> __device__ __forceinline__ u64 FW(u64 x) {
  if (D == 0) return (x >> 1) & NF7;
  if (D == 1) return x >> 8;
  if (D == 2) return (x >> 9) & NF7;
  return (x >> 7) & NF0;            // (1,-1): m[i+1][j-1]
}

// Cells belonging to a maximal run of exactly 1/2/3 along direction D (OR-accumulated).
template<int D> __device__ __forceinline__ void runs(u64 b, u64& r1, u64& r2, u64& r3) {
  u64 f1 = FW<D>(b), f2 = FW<D>(f1), f3 = FW<D>(f2);
  u64 start = b & ~SH<D>(b);
  r1 |= start & ~f1;
  u64 st2 = start & f1 & ~f2;
  r2 |= st2 | SH<D>(st2);
  u64 st3 = start & f1 & f2 & ~f3;
  u64 s3a = SH<D>(st3);
  r3 |= st3 | s3a | SH<D>(s3a);
}

// Line features along rows (D=0) or columns (D=1); OR-accumulated.
template<int D> __device__ __forceinline__ void linefeat(u64 me, u64 op, u64 empty,
                                                         u64& live2, u64& live3, u64& rush3) {
  const u64 EDGE_LO  = (D == 0) ? FILE0 : 0xFFULL;                     // k==0
  const u64 EDGE_HI3 = (D == 0) ? 0xF8F8F8F8F8F8F8F8ULL               // k>=3 (k+5 OOB)
                                : 0xFFFFFFFFFF000000ULL;
  u64 fm1 = FW<D>(me), fm2 = FW<D>(fm1), fm3 = FW<D>(fm2);
  u64 fe1 = FW<D>(empty), fe2 = FW<D>(fe1), fe3 = FW<D>(fe2), fe4 = FW<D>(fe3);
  u64 fn4 = FW<D>(FW<D>(FW<D>(FW<D>(~me))));                          // me[k+4]==0 (in-range)
  // live2: a = me[k] me[k+1] empty[k+2] empty[k+3] -> mark k,k+1
  u64 a = me & fm1 & fe2 & fe3;
  live2 |= a | SH<D>(a);
  // live2: b = empty[k] me[k+1] me[k+2] empty[k+3] -> mark k+1,k+2
  u64 b = empty & fm1 & fm2 & fe3;
  u64 sb = SH<D>(b);
  live2 |= sb | SH<D>(sb);
  // live3: c = empty[k] me[k+1..k+3] empty[k+4] -> mark k+1..k+3
  u64 c = empty & fm1 & fm2 & fm3 & fe4;
  u64 sc = SH<D>(c), sc2 = SH<D>(sc);
  live3 |= sc | sc2 | SH<D>(sc2);
  // blocked(k-1) / blocked(k+5): op there, or off-board
  u64 lb  = SH<D>(op) | EDGE_LO;
  u64 fo5 = FW<D>(FW<D>(FW<D>(FW<D>(FW<D>(op)))));
  u64 rb  = fo5 | EDGE_HI3;
  // rush3 e: open3 (me[k]==0, me[k+1..3]>0, me[k+4]==0) & (lb ^ rb) -> mark k+1..k+3
  u64 open3 = (~me) & fm1 & fm2 & fm3 & fn4;
  u64 e = open3 & (lb ^ rb);
  u64 se = SH<D>(e), se2 = SH<D>(se);
  rush3 |= se | se2 | SH<D>(se2);
  // rush3 d: me[k..k+2], empty[k+3], me[k+4]==0, blocked(k-1) -> mark k..k+2
  u64 d = me & fm1 & fm2 & fe3 & fn4 & lb;
  u64 sd = SH<D>(d);
  rush3 |= d | sd | SH<D>(sd);
}

__global__ __launch_bounds__(256) void Agent_56822417326533_kernel(
    const float* __restrict__ state, const float* __restrict__ side,
    float* __restrict__ out, int B) {
  const int lane = threadIdx.x & 63;
  const int wave = blockIdx.x * (blockDim.x >> 6) + (threadIdx.x >> 6);
  const int board0 = wave * 8;
  if (board0 >= B) return;

  // Phase 1: coalesced load + ballot-assemble bitboards; lane j owns board j.
  u64 my = 0, op = 0;
  const float* sp = state + (size_t)board0 * 64;
  #pragma unroll
  for (int j = 0; j < 8; ++j) {
    if (board0 + j < B) {                 // wave-uniform
      float s = side[board0 + j];
      float v = sp[j * 64 + lane];
      u64 mym = __ballot(v == s);
      u64 opm = __ballot(v == -s);
      if (lane == j) { my = mym; op = opm; }
    }
  }

  u64 empty = ~(my | op);
  u64 ch[18];
  ch[0] = my; ch[1] = op;

  u64 r1m = 0, r2m = 0, r3m = 0, r1o = 0, r2o = 0, r3o = 0;
  runs<0>(my, r1m, r2m, r3m); runs<1>(my, r1m, r2m, r3m);
  runs<2>(my, r1m, r2m, r3m); runs<3>(my, r1m, r2m, r3m);
  runs<0>(op, r1o, r2o, r3o); runs<1>(op, r1o, r2o, r3o);
  runs<2>(op, r1o, r2o, r3o); runs<3>(op, r1o, r2o, r3o);
  ch[2] = r1m; ch[3] = r2m; ch[4] = r3m;
  ch[5] = r1o; ch[6] = r2o; ch[7] = r3o;

  u64 l2m = 0, l3m = 0, ru3m = 0, l2o = 0, l3o = 0, ru3o = 0;
  linefeat<0>(my, op, empty, l2m, l3m, ru3m);
  linefeat<1>(my, op, empty, l2m, l3m, ru3m);
  linefeat<0>(op, my, empty, l2o, l3o, ru3o);
  linefeat<1>(op, my, empty, l2o, l3o, ru3o);
  ch[8] = l2m; ch[9] = l3m; ch[10] = ru3m;
  ch[11] = (__popcll(l2m) >= 2) ? ~0ULL : 0ULL;
  ch[12] = (__popcll(l3m) + __popcll(ru3m) >= 2) ? ~0ULL : 0ULL;
  ch[13] = l2o; ch[14] = l3o; ch[15] = ru3o;
  ch[16] = (__popcll(l2o) >= 2) ? ~0ULL : 0ULL;
  ch[17] = (__popcll(l3o) + __popcll(ru3o) >= 2) ? ~0ULL : 0ULL;

  // Phase 2: coalesced writes — lane i writes bit i of board j / channel c.
  float* outp = out + (size_t)board0 * 1152 + lane;
  #pragma unroll
  for (int j = 0; j < 8; ++j) {
    if (board0 + j < B) {                 // wave-uniform
      #pragma unroll
      for (int c = 0; c < 18; ++c) {
        u64 m = __shfl(ch[c], j);
        outp[j * 1152 + c * 64] = (float)((m >> lane) & 1ULL);
      }
    }
  }
}

extern "C" void kernel_launch(void* const* d_in, const int* in_sizes, int n_in,
                              void* d_out, int out_size, void* d_ws, size_t ws_size,
                              hipStream_t stream) {
  const float* state = (const float*)d_in[0];
  const float* side  = (const float*)d_in[1];
  float* out = (float*)d_out;
  const int B = in_sizes[0] / 64;
  const int boards_per_block = 32;   // 4 waves * 8 boards
  const int blocks = (B + boards_per_block - 1) / boards_per_block;
  hipLaunchKernelGGL(Agent_56822417326533_kernel, dim3(blocks), dim3(256), 0, stream,
                     state, side, out, B);
}

// Round 2
// 159.046 us; speedup vs baseline: 1.0026x; 1.0026x over previous
//
#include <hip/hip_runtime.h>

typedef unsigned long long u64;

#define FILE0 0x0101010101010101ULL  // col j=0
#define NF0   0xFEFEFEFEFEFEFEFEULL  // ~FILE0
#define NF7   0x7F7F7F7F7F7F7F7FULL  // ~FILE7

// Directions: 0=(0,1) rows, 1=(1,0) cols, 2=(1,1) diag, 3=(1,-1) anti-diag
// SH<D>(x): position p reads p-d (backward shift). FW<D>(x): p reads p+d.
template<int D> __device__ __forceinline__ u64 SH(u64 x) {
  if (D == 0) return (x << 1) & NF0;
  if (D == 1) return x << 8;
  if (D == 2) return (x << 9) & NF0;
  return (x << 7) & NF7;            // (1,-1): m[i-1][j+1]
}
template<int D> __device__ __forceinline__ u64 FW(u64 x) {
  if (D == 0) return (x >> 1) & NF7;
  if (D == 1) return x >> 8;
  if (D == 2) return (x >> 9) & NF7;
  return (x >> 7) & NF0;            // (1,-1): m[i+1][j-1]
}

// Cells belonging to a maximal run of exactly 1/2/3 along direction D (OR-accumulated).
template<int D> __device__ __forceinline__ void runs(u64 b, u64& r1, u64& r2, u64& r3) {
  u64 f1 = FW<D>(b), f2 = FW<D>(f1), f3 = FW<D>(f2);
  u64 start = b & ~SH<D>(b);
  r1 |= start & ~f1;
  u64 st2 = start & f1 & ~f2;
  r2 |= st2 | SH<D>(st2);
  u64 st3 = start & f1 & f2 & ~f3;
  u64 s3a = SH<D>(st3);
  r3 |= st3 | s3a | SH<D>(s3a);
}

// Line features along rows (D=0) or columns (D=1); OR-accumulated.
template<int D> __device__ __forceinline__ void linefeat(u64 me, u64 op, u64 empty,
                                                         u64& live2, u64& live3, u64& rush3) {
  const u64 EDGE_LO  = (D == 0) ? FILE0 : 0xFFULL;                     // k==0
  const u64 EDGE_HI3 = (D == 0) ? 0xF8F8F8F8F8F8F8F8ULL               // k>=3 (k+5 OOB)
                                : 0xFFFFFFFFFF000000ULL;
  u64 fm1 = FW<D>(me), fm2 = FW<D>(fm1), fm3 = FW<D>(fm2);
  u64 fe1 = FW<D>(empty), fe2 = FW<D>(fe1), fe3 = FW<D>(fe2), fe4 = FW<D>(fe3);
  u64 fn4 = FW<D>(FW<D>(FW<D>(FW<D>(~me))));                          // me[k+4]==0 (in-range)
  (void)fe1;
  // live2: a = me[k] me[k+1] empty[k+2] empty[k+3] -> mark k,k+1
  u64 a = me & fm1 & fe2 & fe3;
  live2 |= a | SH<D>(a);
  // live2: b = empty[k] me[k+1] me[k+2] empty[k+3] -> mark k+1,k+2
  u64 b = empty & fm1 & fm2 & fe3;
  u64 sb = SH<D>(b);
  live2 |= sb | SH<D>(sb);
  // live3: c = empty[k] me[k+1..k+3] empty[k+4] -> mark k+1..k+3
  u64 c = empty & fm1 & fm2 & fm3 & fe4;
  u64 sc = SH<D>(c), sc2 = SH<D>(sc);
  live3 |= sc | sc2 | SH<D>(sc2);
  // blocked(k-1) / blocked(k+5): op there, or off-board
  u64 lb  = SH<D>(op) | EDGE_LO;
  u64 fo5 = FW<D>(FW<D>(FW<D>(FW<D>(FW<D>(op)))));
  u64 rb  = fo5 | EDGE_HI3;
  // rush3 e: open3 (me[k]==0, me[k+1..3]>0, me[k+4]==0) & (lb ^ rb) -> mark k+1..k+3
  u64 open3 = (~me) & fm1 & fm2 & fm3 & fn4;
  u64 e = open3 & (lb ^ rb);
  u64 se = SH<D>(e), se2 = SH<D>(se);
  rush3 |= se | se2 | SH<D>(se2);
  // rush3 d: me[k..k+2], empty[k+3], me[k+4]==0, blocked(k-1) -> mark k..k+2
  u64 d = me & fm1 & fm2 & fe3 & fn4 & lb;
  u64 sd = SH<D>(d);
  rush3 |= d | sd | SH<D>(sd);
}

__device__ __forceinline__ u64 sel4(int idx, u64 a, u64 b, u64 c, u64 d) {
  u64 ab = (idx & 1) ? b : a;
  u64 cd = (idx & 1) ? d : c;
  return (idx & 2) ? cd : ab;
}

__global__ __launch_bounds__(256) void Agent_56822417326533_kernel(
    const float* __restrict__ state, const float* __restrict__ side,
    float* __restrict__ out, int B) {
  const int lane = threadIdx.x & 63;
  const int board = blockIdx.x * 4 + (threadIdx.x >> 6);
  if (board >= B) return;

  // One wave per board: ballots give wave-uniform bitboards (SGPR pairs);
  // all bitboard math below is uniform -> scalar/VALU mix, no shuffles.
  const float s = side[board];
  const float v = state[(size_t)board * 64 + lane];
  u64 my = __ballot(v == s);
  u64 op = __ballot(v == -s);
  u64 empty = ~(my | op);

  u64 ch[18];
  ch[0] = my; ch[1] = op;

  u64 r1m = 0, r2m = 0, r3m = 0, r1o = 0, r2o = 0, r3o = 0;
  runs<0>(my, r1m, r2m, r3m); runs<1>(my, r1m, r2m, r3m);
  runs<2>(my, r1m, r2m, r3m); runs<3>(my, r1m, r2m, r3m);
  runs<0>(op, r1o, r2o, r3o); runs<1>(op, r1o, r2o, r3o);
  runs<2>(op, r1o, r2o, r3o); runs<3>(op, r1o, r2o, r3o);
  ch[2] = r1m; ch[3] = r2m; ch[4] = r3m;
  ch[5] = r1o; ch[6] = r2o; ch[7] = r3o;

  u64 l2m = 0, l3m = 0, ru3m = 0, l2o = 0, l3o = 0, ru3o = 0;
  linefeat<0>(my, op, empty, l2m, l3m, ru3m);
  linefeat<1>(my, op, empty, l2m, l3m, ru3m);
  linefeat<0>(op, my, empty, l2o, l3o, ru3o);
  linefeat<1>(op, my, empty, l2o, l3o, ru3o);
  ch[8] = l2m; ch[9] = l3m; ch[10] = ru3m;
  ch[11] = (__popcll(l2m) >= 2) ? ~0ULL : 0ULL;
  ch[12] = (__popcll(l3m) + __popcll(ru3m) >= 2) ? ~0ULL : 0ULL;
  ch[13] = l2o; ch[14] = l3o; ch[15] = ru3o;
  ch[16] = (__popcll(l2o) >= 2) ? ~0ULL : 0ULL;
  ch[17] = (__popcll(l3o) + __popcll(ru3o) >= 2) ? ~0ULL : 0ULL;

  // Writes: 1152 floats per board, contiguous. 4x dwordx4 (4 planes each)
  // + 1x dwordx2 (planes 16,17). Lane's channel select among 4 uniform masks.
  float* outp = out + (size_t)board * 1152;
  #pragma unroll
  for (int t = 0; t < 4; ++t) {
    u64 m = sel4(lane >> 4, ch[4 * t], ch[4 * t + 1], ch[4 * t + 2], ch[4 * t + 3]);
    unsigned bits = (unsigned)(m >> ((lane & 15) * 4)) & 0xFu;
    float4 f;
    f.x = (float)(bits & 1u);
    f.y = (float)((bits >> 1) & 1u);
    f.z = (float)((bits >> 2) & 1u);
    f.w = (float)((bits >> 3) & 1u);
    *(float4*)(outp + t * 256 + lane * 4) = f;
  }
  {
    u64 m = (lane & 32) ? ch[17] : ch[16];
    unsigned bits = (unsigned)(m >> ((lane & 31) * 2)) & 0x3u;
    float2 f;
    f.x = (float)(bits & 1u);
    f.y = (float)((bits >> 1) & 1u);
    *(float2*)(outp + 1024 + lane * 2) = f;
  }
}

extern "C" void kernel_launch(void* const* d_in, const int* in_sizes, int n_in,
                              void* d_out, int out_size, void* d_ws, size_t ws_size,
                              hipStream_t stream) {
  const float* state = (const float*)d_in[0];
  const float* side  = (const float*)d_in[1];
  float* out = (float*)d_out;
  const int B = in_sizes[0] / 64;
  const int blocks = (B + 3) / 4;   // 4 waves per block, 1 board per wave
  hipLaunchKernelGGL(Agent_56822417326533_kernel, dim3(blocks), dim3(256), 0, stream,
                     state, side, out, B);
}

// Round 3
// 156.000 us; speedup vs baseline: 1.0222x; 1.0195x over previous
//
#include <hip/hip_runtime.h>

typedef unsigned long long u64;

#define FILE0 0x0101010101010101ULL  // col j=0
#define NF0   0xFEFEFEFEFEFEFEFEULL  // ~FILE0
#define NF7   0x7F7F7F7F7F7F7F7FULL  // ~FILE7

// Directions: 0=(0,1) rows, 1=(1,0) cols, 2=(1,1) diag, 3=(1,-1) anti-diag
// SH<D>(x): position p reads p-d (backward shift). FW<D>(x): p reads p+d.
template<int D> __device__ __forceinline__ u64 SH(u64 x) {
  if (D == 0) return (x << 1) & NF0;
  if (D == 1) return x << 8;
  if (D == 2) return (x << 9) & NF0;
  return (x << 7) & NF7;            // (1,-1): m[i-1][j+1]
}
template<int D> __device__ __forceinline__ u64 FW(u64 x) {
  if (D == 0) return (x >> 1) & NF7;
  if (D == 1) return x >> 8;
  if (D == 2) return (x >> 9) & NF7;
  return (x >> 7) & NF0;            // (1,-1): m[i+1][j-1]
}

// Cells belonging to a maximal run of exactly 1/2/3 along direction D (OR-accumulated).
template<int D> __device__ __forceinline__ void runs(u64 b, u64& r1, u64& r2, u64& r3) {
  u64 f1 = FW<D>(b), f2 = FW<D>(f1), f3 = FW<D>(f2);
  u64 start = b & ~SH<D>(b);
  r1 |= start & ~f1;
  u64 st2 = start & f1 & ~f2;
  r2 |= st2 | SH<D>(st2);
  u64 st3 = start & f1 & f2 & ~f3;
  u64 s3a = SH<D>(st3);
  r3 |= st3 | s3a | SH<D>(s3a);
}

// Line features along rows (D=0) or columns (D=1); OR-accumulated.
template<int D> __device__ __forceinline__ void linefeat(u64 me, u64 op, u64 empty,
                                                         u64& live2, u64& live3, u64& rush3) {
  const u64 EDGE_LO  = (D == 0) ? FILE0 : 0xFFULL;                     // k==0
  const u64 EDGE_HI3 = (D == 0) ? 0xF8F8F8F8F8F8F8F8ULL               // k>=3 (k+5 OOB)
                                : 0xFFFFFFFFFF000000ULL;
  u64 fm1 = FW<D>(me), fm2 = FW<D>(fm1), fm3 = FW<D>(fm2);
  u64 fe2 = FW<D>(FW<D>(empty)), fe3 = FW<D>(fe2), fe4 = FW<D>(fe3);
  u64 fn4 = FW<D>(FW<D>(FW<D>(FW<D>(~me))));                          // me[k+4]==0 (in-range)
  // live2: a = me[k] me[k+1] empty[k+2] empty[k+3] -> mark k,k+1
  u64 a = me & fm1 & fe2 & fe3;
  live2 |= a | SH<D>(a);
  // live2: b = empty[k] me[k+1] me[k+2] empty[k+3] -> mark k+1,k+2
  u64 b = empty & fm1 & fm2 & fe3;
  u64 sb = SH<D>(b);
  live2 |= sb | SH<D>(sb);
  // live3: c = empty[k] me[k+1..k+3] empty[k+4] -> mark k+1..k+3
  u64 c = empty & fm1 & fm2 & fm3 & fe4;
  u64 sc = SH<D>(c), sc2 = SH<D>(sc);
  live3 |= sc | sc2 | SH<D>(sc2);
  // blocked(k-1) / blocked(k+5): op there, or off-board
  u64 lb  = SH<D>(op) | EDGE_LO;
  u64 fo5 = FW<D>(FW<D>(FW<D>(FW<D>(FW<D>(op)))));
  u64 rb  = fo5 | EDGE_HI3;
  // rush3 e: open3 (me[k]==0, me[k+1..3]>0, me[k+4]==0) & (lb ^ rb) -> mark k+1..k+3
  u64 open3 = (~me) & fm1 & fm2 & fm3 & fn4;
  u64 e = open3 & (lb ^ rb);
  u64 se = SH<D>(e), se2 = SH<D>(se);
  rush3 |= se | se2 | SH<D>(se2);
  // rush3 d: me[k..k+2], empty[k+3], me[k+4]==0, blocked(k-1) -> mark k..k+2
  u64 d = me & fm1 & fm2 & fe3 & fn4 & lb;
  u64 sd = SH<D>(d);
  rush3 |= d | sd | SH<D>(sd);
}

__device__ __forceinline__ u64 sel4(int idx, u64 a, u64 b, u64 c, u64 d) {
  u64 ab = (idx & 1) ? b : a;
  u64 cd = (idx & 1) ? d : c;
  return (idx & 2) ? cd : ab;
}

__global__ __launch_bounds__(256) void Agent_56822417326533_kernel(
    const float* __restrict__ state, const float* __restrict__ side,
    float* __restrict__ out, int B) {
  const int lane = threadIdx.x & 63;
  const int wave = blockIdx.x * (blockDim.x >> 6) + (threadIdx.x >> 6);
  const int board0 = wave * 8;
  if (board0 >= B) return;

  // Phase 1: coalesced load + ballot-assemble bitboards; lane j owns board j.
  // (Per-lane VALU compute below — keeps the 600-op u64 chain OFF the shared
  //  scalar pipe, amortized over 8 boards per wave.)
  u64 my = 0, op = 0;
  const float* sp = state + (size_t)board0 * 64;
  #pragma unroll
  for (int j = 0; j < 8; ++j) {
    float s = side[board0 + j];
    float v = sp[j * 64 + lane];
    u64 mym = __ballot(v == s);
    u64 opm = __ballot(v == -s);
    if (lane == j) { my = mym; op = opm; }
  }

  u64 empty = ~(my | op);
  u64 ch[18];
  ch[0] = my; ch[1] = op;

  u64 r1m = 0, r2m = 0, r3m = 0, r1o = 0, r2o = 0, r3o = 0;
  runs<0>(my, r1m, r2m, r3m); runs<1>(my, r1m, r2m, r3m);
  runs<2>(my, r1m, r2m, r3m); runs<3>(my, r1m, r2m, r3m);
  runs<0>(op, r1o, r2o, r3o); runs<1>(op, r1o, r2o, r3o);
  runs<2>(op, r1o, r2o, r3o); runs<3>(op, r1o, r2o, r3o);
  ch[2] = r1m; ch[3] = r2m; ch[4] = r3m;
  ch[5] = r1o; ch[6] = r2o; ch[7] = r3o;

  u64 l2m = 0, l3m = 0, ru3m = 0, l2o = 0, l3o = 0, ru3o = 0;
  linefeat<0>(my, op, empty, l2m, l3m, ru3m);
  linefeat<1>(my, op, empty, l2m, l3m, ru3m);
  linefeat<0>(op, my, empty, l2o, l3o, ru3o);
  linefeat<1>(op, my, empty, l2o, l3o, ru3o);
  ch[8] = l2m; ch[9] = l3m; ch[10] = ru3m;
  ch[11] = (__popcll(l2m) >= 2) ? ~0ULL : 0ULL;
  ch[12] = (__popcll(l3m) + __popcll(ru3m) >= 2) ? ~0ULL : 0ULL;
  ch[13] = l2o; ch[14] = l3o; ch[15] = ru3o;
  ch[16] = (__popcll(l2o) >= 2) ? ~0ULL : 0ULL;
  ch[17] = (__popcll(l3o) + __popcll(ru3o) >= 2) ? ~0ULL : 0ULL;

  // Phase 2: per board j, broadcast its 18 masks to all lanes (shfl = DS pipe),
  // then write with wide stores: 4x dwordx4 (4 planes each) + 1x dwordx2.
  float* outp = out + (size_t)board0 * 1152;
  #pragma unroll
  for (int j = 0; j < 8; ++j) {
    u64 cj[18];
    #pragma unroll
    for (int c = 0; c < 18; ++c) cj[c] = __shfl(ch[c], j);
    float* bp = outp + j * 1152;
    #pragma unroll
    for (int t = 0; t < 4; ++t) {
      u64 m = sel4(lane >> 4, cj[4 * t], cj[4 * t + 1], cj[4 * t + 2], cj[4 * t + 3]);
      unsigned bits = (unsigned)(m >> ((lane & 15) * 4)) & 0xFu;
      float4 f;
      f.x = (float)(bits & 1u);
      f.y = (float)((bits >> 1) & 1u);
      f.z = (float)((bits >> 2) & 1u);
      f.w = (float)((bits >> 3) & 1u);
      *(float4*)(bp + t * 256 + lane * 4) = f;
    }
    {
      u64 m = (lane & 32) ? cj[17] : cj[16];
      unsigned bits = (unsigned)(m >> ((lane & 31) * 2)) & 0x3u;
      float2 f;
      f.x = (float)(bits & 1u);
      f.y = (float)((bits >> 1) & 1u);
      *(float2*)(bp + 1024 + lane * 2) = f;
    }
  }
}

extern "C" void kernel_launch(void* const* d_in, const int* in_sizes, int n_in,
                              void* d_out, int out_size, void* d_ws, size_t ws_size,
                              hipStream_t stream) {
  const float* state = (const float*)d_in[0];
  const float* side  = (const float*)d_in[1];
  float* out = (float*)d_out;
  const int B = in_sizes[0] / 64;
  const int boards_per_block = 32;   // 4 waves * 8 boards
  const int blocks = (B + boards_per_block - 1) / boards_per_block;
  hipLaunchKernelGGL(Agent_56822417326533_kernel, dim3(blocks), dim3(256), 0, stream,
                     state, side, out, B);
}